// Round 4
// baseline (161.354 us; speedup 1.0000x reference)
//
#include <hip/hip_runtime.h>
#include <hip/hip_bf16.h>

// ---------------------------------------------------------------------------
// GCN layer: out = D^{-1/2} (A_set + I) D^{-1/2} @ (x @ W) + bias
// Pipeline (4 dispatches):
//   memset mask (8MB)
//   fused_front: [build_adj (fire-and-forget atomicOr bitmask)
//                 | cast x->bf16 | transpose W | zero Hs pad row + dinv[M]]
//   fused_mid: [gemm 64x64 MFMA BK=64 (B staged with XOR-swizzled source)
//               | build_ell: mask -> ELL list (+self entry, zero-row pads)]
//   spmm: wave = one node, D split in 2 HALVES PINNED TO XCD HALVES.
//     Round-1 lesson: 64-col slices killed the loop shape (8 iters, 8x
//     staging). Round-2 lesson: full-D rows keep the loop long but the
//     8.4MB Hs footprint misses ~50% in the 4MB per-XCD L2 -> ~540MB of
//     gather traffic hits L3. This round: half-D (4.2MB/XCD ~= L2) with
//     half = (bid%8)>=4 so the linear round-robin block->XCD dispatch pins
//     each half to one XCD set; loop stays ~66 iters; staging only 2x.
//     out stores + ell loads are nontemporal so streams don't evict Hs.
// ---------------------------------------------------------------------------

#define ELL_STRIDE 128

typedef __attribute__((ext_vector_type(8))) short bf16x8;
typedef __attribute__((ext_vector_type(4))) float f32x4;

__device__ __forceinline__ unsigned short f2bf(float f) {
  unsigned u = __float_as_uint(f);
  u = (u + 0x7fff + ((u >> 16) & 1)) >> 16;  // RNE
  return (unsigned short)u;
}
__device__ __forceinline__ float bflo(unsigned u) {
  return __uint_as_float(u << 16);
}
__device__ __forceinline__ float bfhi(unsigned u) {
  return __uint_as_float(u & 0xffff0000u);
}

// ---- fused front-end:
// [0,eb): build_adj  [eb,eb+cb): cast  [..+tb): transpose  [last]: pad row
__global__ __launch_bounds__(256) void fused_front_kernel(
    const int* __restrict__ ei, unsigned* __restrict__ mask, int n_edges,
    int words,
    const float* __restrict__ x, unsigned short* __restrict__ xb, int n4,
    const float* __restrict__ W, unsigned short* __restrict__ Wt, int K, int N,
    unsigned short* __restrict__ Hs, float* __restrict__ dinv, int n_nodes,
    int edge_blocks, int cast_blocks, int tr_blocks) {
  const int bid = blockIdx.x;
  if (bid < edge_blocks) {
    const int e = bid * 256 + threadIdx.x;
    if (e < n_edges) {
      const int u = ei[e];
      const int v = ei[e + n_edges];
      // fire-and-forget: never use the return value
      atomicOr(&mask[(size_t)u * words + (v >> 5)], 1u << (v & 31));
      atomicOr(&mask[(size_t)v * words + (u >> 5)], 1u << (u & 31));
    }
    return;
  }
  if (bid < edge_blocks + cast_blocks) {
    const int t = (bid - edge_blocks) * 256 + threadIdx.x;
    if (t < n4) {
      float4 v = ((const float4*)x)[t];
      ushort4 o;
      o.x = f2bf(v.x); o.y = f2bf(v.y); o.z = f2bf(v.z); o.w = f2bf(v.w);
      ((ushort4*)xb)[t] = o;
    }
    return;
  }
  if (bid < edge_blocks + cast_blocks + tr_blocks) {
    // transpose+cast: W[K][N] fp32 -> Wt[N][K] bf16, 32x32 tiles
    __shared__ float tile[32][33];
    const int b = bid - edge_blocks - cast_blocks;
    const int bx = b & ((N >> 5) - 1);
    const int by = b >> (31 - __builtin_clz(N >> 5));
    const int tx = threadIdx.x & 31;
    const int ty = threadIdx.x >> 5;  // 0..7
#pragma unroll
    for (int r = 0; r < 4; ++r)
      tile[ty + 8 * r][tx] = W[(size_t)(by * 32 + ty + 8 * r) * N + bx * 32 + tx];
    __syncthreads();
#pragma unroll
    for (int r = 0; r < 4; ++r)
      Wt[(size_t)(bx * 32 + ty + 8 * r) * K + by * 32 + tx] =
          f2bf(tile[tx][ty + 8 * r]);
    return;
  }
  // zero the ELL pad row Hs[n_nodes][:] and its scale dinv[n_nodes]
  {
    const int t = threadIdx.x;
    if (t < (N >> 1)) ((unsigned*)(Hs + (size_t)n_nodes * N))[t] = 0;
    if (t == 0) dinv[n_nodes] = 0.f;
  }
}

// ---- fused mid: [0,gb): gemm 64x64 BK=64   [gb..): build_ell (wave/node)
__global__ __launch_bounds__(256) void fused_mid_kernel(
    const unsigned short* __restrict__ xb,  // [M][K] bf16
    const unsigned short* __restrict__ Wt,  // [N][K] bf16
    unsigned short* __restrict__ Hs,        // [M+1][N] bf16 (unscaled)
    const unsigned* __restrict__ mask, unsigned short* __restrict__ ell,
    int* __restrict__ deg, float* __restrict__ dinv,
    int M, int N, int K, int words, int gemm_blocks, int nbx_sh) {
  // A slot s: kc=s>>6 (8B k-chunk), row=s&63 -> xb[m0+row][k0+kc*8]
  // B slot s: n=s>>3, kc=s&7  -- STORED with kc XOR (n&7) source pre-swizzle
  //   so the fragment read (stride-128B across lanes, was 16-way same-bank)
  //   spans all 8 bank-quads (both-sides-or-neither swizzle: global source
  //   pre-swizzled because global_load_lds forces a linear LDS dest).
  __shared__ unsigned short As[512 * 8];
  __shared__ unsigned short Bs[512 * 8];

  const int tid = threadIdx.x;
  const int bid = blockIdx.x;

  if (bid < gemm_blocks) {
    const int wave = tid >> 6;
    const int lane = tid & 63;
    const int q = lane >> 4;   // quad
    const int c = lane & 15;
    const int bx = bid & ((1 << nbx_sh) - 1);
    const int by = bid >> nbx_sh;
    const int m0 = by * 64;
    const int n0 = bx * 64;
    const int wr = wave >> 1, wc = wave & 1;

    f32x4 acc[2][2] = {};

    for (int k0 = 0; k0 < K; k0 += 64) {
#pragma unroll
      for (int t = 0; t < 2; ++t) {
        const int sbase = t * 256 + wave * 64;
        const int s = sbase + lane;
        const unsigned short* g =
            xb + (size_t)(m0 + (s & 63)) * K + k0 + (s >> 6) * 8;
        __builtin_amdgcn_global_load_lds(
            (const __attribute__((address_space(1))) void*)g,
            (__attribute__((address_space(3))) void*)(As + sbase * 8), 16, 0, 0);
      }
#pragma unroll
      for (int t = 0; t < 2; ++t) {
        const int sbase = t * 256 + wave * 64;
        const int s = sbase + lane;
        const int bn = s >> 3;
        const int bk = (s & 7) ^ (bn & 7);  // XOR-swizzled source (same 128B seg)
        const unsigned short* g =
            Wt + (size_t)(n0 + bn) * K + k0 + bk * 8;
        __builtin_amdgcn_global_load_lds(
            (const __attribute__((address_space(1))) void*)g,
            (__attribute__((address_space(3))) void*)(Bs + sbase * 8), 16, 0, 0);
      }
      __syncthreads();

#pragma unroll
      for (int kk = 0; kk < 2; ++kk) {
        bf16x8 a[2], b[2];
#pragma unroll
        for (int tm = 0; tm < 2; ++tm) {
          const int row = wr * 32 + tm * 16 + c;
          a[tm] = *(const bf16x8*)(As + (((kk * 4 + q) * 64) + row) * 8);
        }
#pragma unroll
        for (int tn = 0; tn < 2; ++tn) {
          const int n = wc * 32 + tn * 16 + c;
          b[tn] = *(const bf16x8*)(Bs + (n * 8 + ((kk * 4 + q) ^ (n & 7))) * 8);
        }
#pragma unroll
        for (int tm = 0; tm < 2; ++tm)
#pragma unroll
          for (int tn = 0; tn < 2; ++tn)
            acc[tm][tn] = __builtin_amdgcn_mfma_f32_16x16x32_bf16(
                a[tm], b[tn], acc[tm][tn], 0, 0, 0);
      }
      __syncthreads();
    }

    // C/D mapping: col=lane&15, row=quad*4+reg ; unscaled store
#pragma unroll
    for (int tm = 0; tm < 2; ++tm) {
#pragma unroll
      for (int r = 0; r < 4; ++r) {
        const int grow = m0 + wr * 32 + tm * 16 + q * 4 + r;
#pragma unroll
        for (int tn = 0; tn < 2; ++tn) {
          const int gcol = n0 + wc * 32 + tn * 16 + c;
          Hs[(size_t)grow * N + gcol] = f2bf(acc[tm][tn][r]);
        }
      }
    }
    return;
  }

  // ---- build_ell: one wave per node, popcount + lane prefix-scan.
  {
    const int wave = tid >> 6, lane = tid & 63;
    const int node = (bid - gemm_blocks) * 4 + wave;
    const unsigned* __restrict__ row = mask + (size_t)node * words;
    unsigned short* __restrict__ out = ell + (size_t)node * ELL_STRIDE;

    int running = 0;
    for (int r = 0; r < words; r += 64) {
      const int w = r + lane;
      unsigned bits = row[w];
      const int cnt = __popc(bits);
      int x = cnt;
#pragma unroll
      for (int d = 1; d < 64; d <<= 1) {
        int y = __shfl_up(x, d, 64);
        if (lane >= d) x += y;
      }
      int pos = running + x - cnt;
      while (bits) {
        const int b = __builtin_ctz(bits);
        bits &= bits - 1;
        if (pos < ELL_STRIDE) out[pos] = (unsigned short)((w << 5) + b);
        ++pos;
      }
      running += __shfl(x, 63, 64);
    }
    // self entry at [running], pads (index M -> dinv 0, zero row) after
    for (int p = running + lane; p < ELL_STRIDE; p += 64)
      out[p] = (unsigned short)(p == running ? node : M);
    if (lane == 0) {
      const int dd = running + 1;  // + self
      deg[node] = dd < ELL_STRIDE ? dd : ELL_STRIDE;
      dinv[node] = rsqrtf((float)running + 1.0f);
    }
  }
}

// ---- spmm: grid 2*(n/4) blocks; wave = one node, HALF of D per wave.
// half = (bid%8)>=4: the linear round-robin block->XCD dispatch pins
// cols [0,256) to XCDs 0-3 and [256,512) to XCDs 4-7, so each XCD's
// gather working set is 4.2MB ~= its 4MB L2 (was 8.4MB -> 50% miss).
// 64 lanes x 8B = one 512B half-row per iter, fully coalesced; ~66 iters.
// (byte_offset, dinv_j) staged once per wave in LDS; each lane owns 4
// output cols -> no cross-lane reduce. ell loads + out stores are
// nontemporal so the streams don't evict the Hs working set from L2.
__global__ __launch_bounds__(256) void spmm_kernel(
    const unsigned short* __restrict__ ell, const int* __restrict__ deg,
    const float* __restrict__ dinv, const unsigned short* __restrict__ Hs,
    const float* __restrict__ bias, float* __restrict__ out, int n, int D) {
  __shared__ uint2 ji[4][ELL_STRIDE];
  const int wave = threadIdx.x >> 6, lane = threadIdx.x & 63;
  const int bid = blockIdx.x;
  const int xcd = bid & 7;
  const int half = xcd >> 2;                 // XCDs 0-3 -> half 0; 4-7 -> half 1
  const int g = (bid >> 3) * 4 + (xcd & 3);  // node group, bijective for n/4 % 4 == 0
  const int i = g * 4 + wave;                // node
  const unsigned rowbytes = (unsigned)(D * 2);

  {  // stage (byte offset, dinv[j]) — 2 entries per lane; dinv is 32KB -> L1
    const unsigned j0 =
        __builtin_nontemporal_load(ell + (size_t)i * ELL_STRIDE + lane);
    const unsigned j1 =
        __builtin_nontemporal_load(ell + (size_t)i * ELL_STRIDE + 64 + lane);
    ji[wave][lane] = make_uint2(j0 * rowbytes, __float_as_uint(dinv[j0]));
    ji[wave][64 + lane] = make_uint2(j1 * rowbytes, __float_as_uint(dinv[j1]));
  }
  const int d = deg[i];            // includes the self entry
  const float di = dinv[i];
  const int kmax = (d + 7) & ~7;   // pads (dinv 0, zero row) cover the tail

  // this wave reads bytes [half*D, half*D+512) of each row: 8B per lane
  const char* __restrict__ hb = (const char*)Hs + half * D + lane * 8;
  float acc[4] = {0.f, 0.f, 0.f, 0.f};

#pragma unroll 8
  for (int k = 0; k < kmax; ++k) {
    const uint2 e = ji[wave][k];  // uniform addr -> LDS broadcast
    const float dj = __uint_as_float(e.y);
    const uint2 hv = *(const uint2*)(hb + e.x);
    acc[0] += dj * bflo(hv.x); acc[1] += dj * bfhi(hv.x);
    acc[2] += dj * bflo(hv.y); acc[3] += dj * bfhi(hv.y);
  }

  const int col = half * (D >> 1) + lane * 4;
  const float4 b0 = *(const float4*)(bias + col);
  f32x4 o0;
  o0.x = di * acc[0] + b0.x; o0.y = di * acc[1] + b0.y;
  o0.z = di * acc[2] + b0.z; o0.w = di * acc[3] + b0.w;
  // native clang vector type for the nontemporal builtin (HIP float4 is a
  // class and is rejected); same 16B global_store_dwordx4 nt.
  __builtin_nontemporal_store(o0, (f32x4*)(out + (size_t)i * D + col));
}

extern "C" void kernel_launch(void* const* d_in, const int* in_sizes, int n_in,
                              void* d_out, int out_size, void* d_ws, size_t ws_size,
                              hipStream_t stream) {
  const float* x    = (const float*)d_in[0];
  const int*   ei   = (const int*)d_in[1];
  const float* W    = (const float*)d_in[2];
  const float* bias = (const float*)d_in[3];
  float* out = (float*)d_out;

  const int d_out_dim = in_sizes[3];             // 512
  const int d_in_dim  = in_sizes[2] / d_out_dim; // 512
  const int n_nodes   = in_sizes[0] / d_in_dim;  // 8192
  const int n_edges   = in_sizes[1] / 2;         // 262144
  const int words     = (n_nodes + 31) / 32;     // 256

  // workspace layout (bytes)
  char* ws = (char*)d_ws;
  size_t off = 0;
  unsigned* mask = (unsigned*)(ws + off); off += (size_t)n_nodes * words * 4;       // 8 MB
  int* deg       = (int*)(ws + off);      off += (size_t)n_nodes * 4;               // 32 KB
  float* dinv    = (float*)(ws + off);    off += (size_t)(n_nodes + 1) * 4;         // 32 KB + pad
  unsigned short* ell = (unsigned short*)(ws + off); off += (size_t)n_nodes * ELL_STRIDE * 2; // 2 MB
  unsigned short* xb  = (unsigned short*)(ws + off); off += (size_t)n_nodes * d_in_dim * 2;   // 8 MB
  unsigned short* Wt  = (unsigned short*)(ws + off); off += (size_t)d_in_dim * d_out_dim * 2; // 512 KB
  unsigned short* Hs  = (unsigned short*)(ws + off);
  off += (size_t)(n_nodes + 1) * d_out_dim * 2;  // 8 MB + pad row

  hipMemsetAsync(mask, 0, (size_t)n_nodes * words * 4, stream);

  const int edge_blocks = (n_edges + 255) / 256;              // 1024
  const int n4 = n_nodes * d_in_dim / 4;
  const int cast_blocks = (n4 + 255) / 256;                   // 4096
  const int tr_blocks = (d_in_dim / 32) * (d_out_dim / 32);   // 256
  fused_front_kernel<<<edge_blocks + cast_blocks + tr_blocks + 1, 256, 0, stream>>>(
      ei, mask, n_edges, words, x, xb, n4, W, Wt, d_in_dim, d_out_dim,
      Hs, dinv, n_nodes, edge_blocks, cast_blocks, tr_blocks);

  const int nbx = d_out_dim / 64;                             // 8
  const int nbx_sh = 31 - __builtin_clz(nbx);                 // 3
  const int gemm_blocks = nbx * (n_nodes / 64);               // 1024
  const int ell_blocks = n_nodes / 4;                         // 2048
  fused_mid_kernel<<<gemm_blocks + ell_blocks, 256, 0, stream>>>(
      xb, Wt, Hs, mask, ell, deg, dinv,
      n_nodes, d_out_dim, d_in_dim, words, gemm_blocks, nbx_sh);

  const int spmm_blocks = 2 * (n_nodes / 4);                  // 4096
  spmm_kernel<<<spmm_blocks, 256, 0, stream>>>(ell, deg, dinv, Hs, bias, out,
                                               n_nodes, d_out_dim);
}

// Round 5
// 161.331 us; speedup vs baseline: 1.0001x; 1.0001x over previous
//
#include <hip/hip_runtime.h>
#include <hip/hip_bf16.h>

// ---------------------------------------------------------------------------
// GCN layer: out = D^{-1/2} (A_set + I) D^{-1/2} @ (x @ W) + bias
// Pipeline (4 dispatches):
//   memset mask (8MB)
//   fused_front: [build_adj | cast x->bf16 | transpose W | pad row]
//   fused_mid: [gemm 64x64 MFMA BK=64 (XOR-swizzled B) | build_ell]
//   spmm: wave = one node, QUARTER of D (128 cols), quarter pinned to an
//     XCD PAIR via quarter=(bid%8)>>1.
//     Ledger: r1: 64-col slices -> L2-resident (FETCH 16.6MB) but 8-iter
//     loops + 8x staging = 58us. r2: full-D -> good shape but 8.4MB/XCD
//     footprint, ~45us. r4: half-D -> 4.2MB vs 4.0MB L2 = random-access
//     thrash, FETCH 80MB, 47us. This round: 2.1MB/XCD (<<4MB, margin for
//     the out stream) AND ~66-entry loops. Lane shape: 16-lane group per
//     ELL entry, 16B/lane dwordx4 (16x16B = 256B = quarter row), 4 entries
//     in flight -> LDS/addr cost amortized over 16B, VALU ~9us floor.
// ---------------------------------------------------------------------------

#define ELL_STRIDE 128

typedef __attribute__((ext_vector_type(8))) short bf16x8;
typedef __attribute__((ext_vector_type(4))) float f32x4;

__device__ __forceinline__ unsigned short f2bf(float f) {
  unsigned u = __float_as_uint(f);
  u = (u + 0x7fff + ((u >> 16) & 1)) >> 16;  // RNE
  return (unsigned short)u;
}
__device__ __forceinline__ float bflo(unsigned u) {
  return __uint_as_float(u << 16);
}
__device__ __forceinline__ float bfhi(unsigned u) {
  return __uint_as_float(u & 0xffff0000u);
}

// ---- fused front-end:
// [0,eb): build_adj  [eb,eb+cb): cast  [..+tb): transpose  [last]: pad row
__global__ __launch_bounds__(256) void fused_front_kernel(
    const int* __restrict__ ei, unsigned* __restrict__ mask, int n_edges,
    int words,
    const float* __restrict__ x, unsigned short* __restrict__ xb, int n4,
    const float* __restrict__ W, unsigned short* __restrict__ Wt, int K, int N,
    unsigned short* __restrict__ Hs, float* __restrict__ dinv, int n_nodes,
    int edge_blocks, int cast_blocks, int tr_blocks) {
  const int bid = blockIdx.x;
  if (bid < edge_blocks) {
    const int e = bid * 256 + threadIdx.x;
    if (e < n_edges) {
      const int u = ei[e];
      const int v = ei[e + n_edges];
      // fire-and-forget: never use the return value
      atomicOr(&mask[(size_t)u * words + (v >> 5)], 1u << (v & 31));
      atomicOr(&mask[(size_t)v * words + (u >> 5)], 1u << (u & 31));
    }
    return;
  }
  if (bid < edge_blocks + cast_blocks) {
    const int t = (bid - edge_blocks) * 256 + threadIdx.x;
    if (t < n4) {
      float4 v = ((const float4*)x)[t];
      ushort4 o;
      o.x = f2bf(v.x); o.y = f2bf(v.y); o.z = f2bf(v.z); o.w = f2bf(v.w);
      ((ushort4*)xb)[t] = o;
    }
    return;
  }
  if (bid < edge_blocks + cast_blocks + tr_blocks) {
    // transpose+cast: W[K][N] fp32 -> Wt[N][K] bf16, 32x32 tiles
    __shared__ float tile[32][33];
    const int b = bid - edge_blocks - cast_blocks;
    const int bx = b & ((N >> 5) - 1);
    const int by = b >> (31 - __builtin_clz(N >> 5));
    const int tx = threadIdx.x & 31;
    const int ty = threadIdx.x >> 5;  // 0..7
#pragma unroll
    for (int r = 0; r < 4; ++r)
      tile[ty + 8 * r][tx] = W[(size_t)(by * 32 + ty + 8 * r) * N + bx * 32 + tx];
    __syncthreads();
#pragma unroll
    for (int r = 0; r < 4; ++r)
      Wt[(size_t)(bx * 32 + ty + 8 * r) * K + by * 32 + tx] =
          f2bf(tile[tx][ty + 8 * r]);
    return;
  }
  // zero the ELL pad row Hs[n_nodes][:] and its scale dinv[n_nodes]
  {
    const int t = threadIdx.x;
    if (t < (N >> 1)) ((unsigned*)(Hs + (size_t)n_nodes * N))[t] = 0;
    if (t == 0) dinv[n_nodes] = 0.f;
  }
}

// ---- fused mid: [0,gb): gemm 64x64 BK=64   [gb..): build_ell (wave/node)
__global__ __launch_bounds__(256) void fused_mid_kernel(
    const unsigned short* __restrict__ xb,  // [M][K] bf16
    const unsigned short* __restrict__ Wt,  // [N][K] bf16
    unsigned short* __restrict__ Hs,        // [M+1][N] bf16 (unscaled)
    const unsigned* __restrict__ mask, unsigned short* __restrict__ ell,
    int* __restrict__ deg, float* __restrict__ dinv,
    int M, int N, int K, int words, int gemm_blocks, int nbx_sh) {
  // A slot s: kc=s>>6 (8B k-chunk), row=s&63 -> xb[m0+row][k0+kc*8]
  // B slot s: n=s>>3, kc=s&7  -- STORED with kc XOR (n&7) source pre-swizzle
  //   so the fragment read (stride-128B across lanes, was 16-way same-bank)
  //   spans all 8 bank-quads (both-sides-or-neither swizzle: global source
  //   pre-swizzled because global_load_lds forces a linear LDS dest).
  __shared__ unsigned short As[512 * 8];
  __shared__ unsigned short Bs[512 * 8];

  const int tid = threadIdx.x;
  const int bid = blockIdx.x;

  if (bid < gemm_blocks) {
    const int wave = tid >> 6;
    const int lane = tid & 63;
    const int q = lane >> 4;   // quad
    const int c = lane & 15;
    const int bx = bid & ((1 << nbx_sh) - 1);
    const int by = bid >> nbx_sh;
    const int m0 = by * 64;
    const int n0 = bx * 64;
    const int wr = wave >> 1, wc = wave & 1;

    f32x4 acc[2][2] = {};

    for (int k0 = 0; k0 < K; k0 += 64) {
#pragma unroll
      for (int t = 0; t < 2; ++t) {
        const int sbase = t * 256 + wave * 64;
        const int s = sbase + lane;
        const unsigned short* g =
            xb + (size_t)(m0 + (s & 63)) * K + k0 + (s >> 6) * 8;
        __builtin_amdgcn_global_load_lds(
            (const __attribute__((address_space(1))) void*)g,
            (__attribute__((address_space(3))) void*)(As + sbase * 8), 16, 0, 0);
      }
#pragma unroll
      for (int t = 0; t < 2; ++t) {
        const int sbase = t * 256 + wave * 64;
        const int s = sbase + lane;
        const int bn = s >> 3;
        const int bk = (s & 7) ^ (bn & 7);  // XOR-swizzled source (same 128B seg)
        const unsigned short* g =
            Wt + (size_t)(n0 + bn) * K + k0 + bk * 8;
        __builtin_amdgcn_global_load_lds(
            (const __attribute__((address_space(1))) void*)g,
            (__attribute__((address_space(3))) void*)(Bs + sbase * 8), 16, 0, 0);
      }
      __syncthreads();

#pragma unroll
      for (int kk = 0; kk < 2; ++kk) {
        bf16x8 a[2], b[2];
#pragma unroll
        for (int tm = 0; tm < 2; ++tm) {
          const int row = wr * 32 + tm * 16 + c;
          a[tm] = *(const bf16x8*)(As + (((kk * 4 + q) * 64) + row) * 8);
        }
#pragma unroll
        for (int tn = 0; tn < 2; ++tn) {
          const int n = wc * 32 + tn * 16 + c;
          b[tn] = *(const bf16x8*)(Bs + (n * 8 + ((kk * 4 + q) ^ (n & 7))) * 8);
        }
#pragma unroll
        for (int tm = 0; tm < 2; ++tm)
#pragma unroll
          for (int tn = 0; tn < 2; ++tn)
            acc[tm][tn] = __builtin_amdgcn_mfma_f32_16x16x32_bf16(
                a[tm], b[tn], acc[tm][tn], 0, 0, 0);
      }
      __syncthreads();
    }

    // C/D mapping: col=lane&15, row=quad*4+reg ; unscaled store
#pragma unroll
    for (int tm = 0; tm < 2; ++tm) {
#pragma unroll
      for (int r = 0; r < 4; ++r) {
        const int grow = m0 + wr * 32 + tm * 16 + q * 4 + r;
#pragma unroll
        for (int tn = 0; tn < 2; ++tn) {
          const int gcol = n0 + wc * 32 + tn * 16 + c;
          Hs[(size_t)grow * N + gcol] = f2bf(acc[tm][tn][r]);
        }
      }
    }
    return;
  }

  // ---- build_ell: one wave per node, popcount + lane prefix-scan.
  {
    const int wave = tid >> 6, lane = tid & 63;
    const int node = (bid - gemm_blocks) * 4 + wave;
    const unsigned* __restrict__ row = mask + (size_t)node * words;
    unsigned short* __restrict__ out = ell + (size_t)node * ELL_STRIDE;

    int running = 0;
    for (int r = 0; r < words; r += 64) {
      const int w = r + lane;
      unsigned bits = row[w];
      const int cnt = __popc(bits);
      int x = cnt;
#pragma unroll
      for (int d = 1; d < 64; d <<= 1) {
        int y = __shfl_up(x, d, 64);
        if (lane >= d) x += y;
      }
      int pos = running + x - cnt;
      while (bits) {
        const int b = __builtin_ctz(bits);
        bits &= bits - 1;
        if (pos < ELL_STRIDE) out[pos] = (unsigned short)((w << 5) + b);
        ++pos;
      }
      running += __shfl(x, 63, 64);
    }
    // self entry at [running], pads (index M -> dinv 0, zero row) after
    for (int p = running + lane; p < ELL_STRIDE; p += 64)
      out[p] = (unsigned short)(p == running ? node : M);
    if (lane == 0) {
      const int dd = running + 1;  // + self
      deg[node] = dd < ELL_STRIDE ? dd : ELL_STRIDE;
      dinv[node] = rsqrtf((float)running + 1.0f);
    }
  }
}

// ---- spmm: grid 4*(n/4) blocks; wave = one node, QUARTER of D per wave.
// quarter = (bid%8)>>1: linear round-robin block->XCD dispatch pins
// quarter q to XCD pair {2q,2q+1} -> 2.1MB gather working set per XCD,
// comfortably inside the 4MB L2 (r4 lesson: 4.2MB thrashed, FETCH 80MB).
// Lane shape: 16-lane group per ELL entry, 16B/lane dwordx4; 16x16B=256B =
// one quarter-row; 4 entries in flight per iter -> LDS/addr amortized.
// (byte_offset, dinv_j) staged once per wave in LDS. shfl_xor(16,32)
// reduce across the 4 groups at the end. ell loads + out stores
// nontemporal so streams don't evict the Hs working set from L2.
__global__ __launch_bounds__(256) void spmm_kernel(
    const unsigned short* __restrict__ ell, const int* __restrict__ deg,
    const float* __restrict__ dinv, const unsigned short* __restrict__ Hs,
    const float* __restrict__ bias, float* __restrict__ out, int n, int D) {
  __shared__ uint2 ji[4][ELL_STRIDE];
  const int wave = threadIdx.x >> 6, lane = threadIdx.x & 63;
  const int bid = blockIdx.x;
  const int xcd = bid & 7;
  const int qt = xcd >> 1;                   // quarter pinned to XCD pair
  const int g = (bid >> 3) * 2 + (xcd & 1);  // node group, bijective
  const int i = g * 4 + wave;                // node
  const int e = lane >> 4, hl = lane & 15;   // entry slot, lane-in-group
  const unsigned rowbytes = (unsigned)(D * 2);

  {  // stage (byte offset, dinv[j]) — 2 entries per lane; dinv is 32KB -> L1
    const unsigned j0 =
        __builtin_nontemporal_load(ell + (size_t)i * ELL_STRIDE + lane);
    const unsigned j1 =
        __builtin_nontemporal_load(ell + (size_t)i * ELL_STRIDE + 64 + lane);
    ji[wave][lane] = make_uint2(j0 * rowbytes, __float_as_uint(dinv[j0]));
    ji[wave][64 + lane] = make_uint2(j1 * rowbytes, __float_as_uint(dinv[j1]));
  }
  const int d = deg[i];            // includes the self entry
  const float di = dinv[i];
  const int kmax = (d + 3) & ~3;   // pads (dinv 0, zero row) cover the tail

  // this wave reads bytes [qt*256, qt*256+256) of each row: 16B per lane
  const char* __restrict__ hb = (const char*)Hs + qt * 256 + hl * 16;
  float acc[8] = {0.f, 0.f, 0.f, 0.f, 0.f, 0.f, 0.f, 0.f};

#pragma unroll 8
  for (int k = 0; k < kmax; k += 4) {
    const uint2 t = ji[wave][k + e];  // 4 addrs/wave, 16-lane broadcast each
    const float dj = __uint_as_float(t.y);
    const uint4 hv = *(const uint4*)(hb + t.x);
    acc[0] += dj * bflo(hv.x); acc[1] += dj * bfhi(hv.x);
    acc[2] += dj * bflo(hv.y); acc[3] += dj * bfhi(hv.y);
    acc[4] += dj * bflo(hv.z); acc[5] += dj * bfhi(hv.z);
    acc[6] += dj * bflo(hv.w); acc[7] += dj * bfhi(hv.w);
  }
#pragma unroll
  for (int t = 0; t < 8; ++t) {
    acc[t] += __shfl_xor(acc[t], 16, 64);
    acc[t] += __shfl_xor(acc[t], 32, 64);
  }

  if (lane < 16) {  // lane == hl, e == 0
    const int col = qt * (D >> 2) + lane * 8;
    const float4 b0 = *(const float4*)(bias + col);
    const float4 b1 = *(const float4*)(bias + col + 4);
    float* op = out + (size_t)i * D + col;
    f32x4 o0, o1;
    o0.x = di * acc[0] + b0.x; o0.y = di * acc[1] + b0.y;
    o0.z = di * acc[2] + b0.z; o0.w = di * acc[3] + b0.w;
    o1.x = di * acc[4] + b1.x; o1.y = di * acc[5] + b1.y;
    o1.z = di * acc[6] + b1.z; o1.w = di * acc[7] + b1.w;
    __builtin_nontemporal_store(o0, (f32x4*)op);
    __builtin_nontemporal_store(o1, (f32x4*)(op + 4));
  }
}

extern "C" void kernel_launch(void* const* d_in, const int* in_sizes, int n_in,
                              void* d_out, int out_size, void* d_ws, size_t ws_size,
                              hipStream_t stream) {
  const float* x    = (const float*)d_in[0];
  const int*   ei   = (const int*)d_in[1];
  const float* W    = (const float*)d_in[2];
  const float* bias = (const float*)d_in[3];
  float* out = (float*)d_out;

  const int d_out_dim = in_sizes[3];             // 512
  const int d_in_dim  = in_sizes[2] / d_out_dim; // 512
  const int n_nodes   = in_sizes[0] / d_in_dim;  // 8192
  const int n_edges   = in_sizes[1] / 2;         // 262144
  const int words     = (n_nodes + 31) / 32;     // 256

  // workspace layout (bytes)
  char* ws = (char*)d_ws;
  size_t off = 0;
  unsigned* mask = (unsigned*)(ws + off); off += (size_t)n_nodes * words * 4;       // 8 MB
  int* deg       = (int*)(ws + off);      off += (size_t)n_nodes * 4;               // 32 KB
  float* dinv    = (float*)(ws + off);    off += (size_t)(n_nodes + 1) * 4;         // 32 KB + pad
  unsigned short* ell = (unsigned short*)(ws + off); off += (size_t)n_nodes * ELL_STRIDE * 2; // 2 MB
  unsigned short* xb  = (unsigned short*)(ws + off); off += (size_t)n_nodes * d_in_dim * 2;   // 8 MB
  unsigned short* Wt  = (unsigned short*)(ws + off); off += (size_t)d_in_dim * d_out_dim * 2; // 512 KB
  unsigned short* Hs  = (unsigned short*)(ws + off);
  off += (size_t)(n_nodes + 1) * d_out_dim * 2;  // 8 MB + pad row

  hipMemsetAsync(mask, 0, (size_t)n_nodes * words * 4, stream);

  const int edge_blocks = (n_edges + 255) / 256;              // 1024
  const int n4 = n_nodes * d_in_dim / 4;
  const int cast_blocks = (n4 + 255) / 256;                   // 4096
  const int tr_blocks = (d_in_dim / 32) * (d_out_dim / 32);   // 256
  fused_front_kernel<<<edge_blocks + cast_blocks + tr_blocks + 1, 256, 0, stream>>>(
      ei, mask, n_edges, words, x, xb, n4, W, Wt, d_in_dim, d_out_dim,
      Hs, dinv, n_nodes, edge_blocks, cast_blocks, tr_blocks);

  const int nbx = d_out_dim / 64;                             // 8
  const int nbx_sh = 31 - __builtin_clz(nbx);                 // 3
  const int gemm_blocks = nbx * (n_nodes / 64);               // 1024
  const int ell_blocks = n_nodes / 4;                         // 2048
  fused_mid_kernel<<<gemm_blocks + ell_blocks, 256, 0, stream>>>(
      xb, Wt, Hs, mask, ell, deg, dinv,
      n_nodes, d_out_dim, d_in_dim, words, gemm_blocks, nbx_sh);

  const int spmm_blocks = 4 * (n_nodes / 4);                  // 8192
  spmm_kernel<<<spmm_blocks, 256, 0, stream>>>(ell, deg, dinv, Hs, bias, out,
                                               n_nodes, d_out_dim);
}

// Round 6
// 160.242 us; speedup vs baseline: 1.0069x; 1.0068x over previous
//
#include <hip/hip_runtime.h>
#include <hip/hip_bf16.h>

// ---------------------------------------------------------------------------
// GCN layer: out = D^{-1/2} (A_set + I) D^{-1/2} @ (x @ W) + bias
// Pipeline (4 dispatches):
//   memset mask (8MB)
//   fused_front: [build_adj | cast x->bf16 | transpose W | pad row]
//   fused_mid: [gemm 128x128 MFMA BK=64 (XOR-swizzled B) | build_ell]
//   spmm: wave = one node, FULL D row per entry (64 lanes x 16B = 1KB),
//     unroll 16.
//   spmm shape ledger (dur / FETCH): r1 64-col slices: 58us/16.6MB.
//     r2 full-D: <=45us. r4 half-D: 47us/80MB (L2 thrash). r5 quarter-D
//     XCD-pinned: 48us/17MB. CONCLUSION: time is INVARIANT to L2 miss
//     traffic -> spmm is latency/issue-bound, not locality-bound. Keep the
//     best shape (full-D, least staging, ~66-iter loop) and raise memory-
//     level parallelism (unroll 16) instead of chasing locality.
// ---------------------------------------------------------------------------

#define ELL_STRIDE 128

typedef __attribute__((ext_vector_type(8))) short bf16x8;
typedef __attribute__((ext_vector_type(4))) float f32x4;

__device__ __forceinline__ unsigned short f2bf(float f) {
  unsigned u = __float_as_uint(f);
  u = (u + 0x7fff + ((u >> 16) & 1)) >> 16;  // RNE
  return (unsigned short)u;
}
__device__ __forceinline__ float bflo(unsigned u) {
  return __uint_as_float(u << 16);
}
__device__ __forceinline__ float bfhi(unsigned u) {
  return __uint_as_float(u & 0xffff0000u);
}

// ---- fused front-end:
// [0,eb): build_adj  [eb,eb+cb): cast  [..+tb): transpose  [last]: pad row
__global__ __launch_bounds__(256) void fused_front_kernel(
    const int* __restrict__ ei, unsigned* __restrict__ mask, int n_edges,
    int words,
    const float* __restrict__ x, unsigned short* __restrict__ xb, int n4,
    const float* __restrict__ W, unsigned short* __restrict__ Wt, int K, int N,
    unsigned short* __restrict__ Hs, float* __restrict__ dinv, int n_nodes,
    int edge_blocks, int cast_blocks, int tr_blocks) {
  const int bid = blockIdx.x;
  if (bid < edge_blocks) {
    const int e = bid * 256 + threadIdx.x;
    if (e < n_edges) {
      const int u = ei[e];
      const int v = ei[e + n_edges];
      // fire-and-forget: never use the return value
      atomicOr(&mask[(size_t)u * words + (v >> 5)], 1u << (v & 31));
      atomicOr(&mask[(size_t)v * words + (u >> 5)], 1u << (u & 31));
    }
    return;
  }
  if (bid < edge_blocks + cast_blocks) {
    const int t = (bid - edge_blocks) * 256 + threadIdx.x;
    if (t < n4) {
      float4 v = ((const float4*)x)[t];
      ushort4 o;
      o.x = f2bf(v.x); o.y = f2bf(v.y); o.z = f2bf(v.z); o.w = f2bf(v.w);
      ((ushort4*)xb)[t] = o;
    }
    return;
  }
  if (bid < edge_blocks + cast_blocks + tr_blocks) {
    // transpose+cast: W[K][N] fp32 -> Wt[N][K] bf16, 32x32 tiles
    __shared__ float tile[32][33];
    const int b = bid - edge_blocks - cast_blocks;
    const int bx = b & ((N >> 5) - 1);
    const int by = b >> (31 - __builtin_clz(N >> 5));
    const int tx = threadIdx.x & 31;
    const int ty = threadIdx.x >> 5;  // 0..7
#pragma unroll
    for (int r = 0; r < 4; ++r)
      tile[ty + 8 * r][tx] = W[(size_t)(by * 32 + ty + 8 * r) * N + bx * 32 + tx];
    __syncthreads();
#pragma unroll
    for (int r = 0; r < 4; ++r)
      Wt[(size_t)(bx * 32 + ty + 8 * r) * K + by * 32 + tx] =
          f2bf(tile[tx][ty + 8 * r]);
    return;
  }
  // zero the ELL pad row Hs[n_nodes][:] and its scale dinv[n_nodes]
  {
    const int t = threadIdx.x;
    if (t < (N >> 1)) ((unsigned*)(Hs + (size_t)n_nodes * N))[t] = 0;
    if (t == 0) dinv[n_nodes] = 0.f;
  }
}

// ---- fused mid: [0,gb): gemm 128x128 BK=64   [gb..): build_ell (wave/node)
__global__ __launch_bounds__(256) void fused_mid_kernel(
    const unsigned short* __restrict__ xb,  // [M][K] bf16
    const unsigned short* __restrict__ Wt,  // [N][K] bf16
    unsigned short* __restrict__ Hs,        // [M+1][N] bf16 (unscaled)
    const unsigned* __restrict__ mask, unsigned short* __restrict__ ell,
    int* __restrict__ deg, float* __restrict__ dinv,
    int M, int N, int K, int words, int gemm_blocks, int nbx_sh) {
  // 128x128 tile, BK=64, 4 waves in 2x2, each wave -> 64x64 output (4x4
  // frags of 16x16x32). 2x MFMA per ds_read and per staged byte vs the old
  // 64x64 tile (m93/97 ladder step: 343 -> ~900 TF class).
  // A slot s (0..1023): row=s&127, kc=s>>7 -> xb[m0+row][k0+kc*8]
  // B slot s (0..1023): bn=s>>3, bk=(s&7)^(bn&7)  (XOR source pre-swizzle so
  //   the stride-128B fragment read spans all 8 bank-quads; global source
  //   swizzled because global_load_lds forces a linear LDS dest).
  __shared__ unsigned short As[1024 * 8];
  __shared__ unsigned short Bs[1024 * 8];

  const int tid = threadIdx.x;
  const int bid = blockIdx.x;

  if (bid < gemm_blocks) {
    const int wave = tid >> 6;
    const int lane = tid & 63;
    const int q = lane >> 4;   // quad
    const int c = lane & 15;
    const int bx = bid & ((1 << nbx_sh) - 1);
    const int by = bid >> nbx_sh;
    const int m0 = by * 128;
    const int n0 = bx * 128;
    const int wr = wave >> 1, wc = wave & 1;

    f32x4 acc[4][4] = {};

    for (int k0 = 0; k0 < K; k0 += 64) {
#pragma unroll
      for (int t = 0; t < 4; ++t) {
        const int sbase = t * 256 + wave * 64;
        const int s = sbase + lane;
        const unsigned short* g =
            xb + (size_t)(m0 + (s & 127)) * K + k0 + (s >> 7) * 8;
        __builtin_amdgcn_global_load_lds(
            (const __attribute__((address_space(1))) void*)g,
            (__attribute__((address_space(3))) void*)(As + sbase * 8), 16, 0, 0);
      }
#pragma unroll
      for (int t = 0; t < 4; ++t) {
        const int sbase = t * 256 + wave * 64;
        const int s = sbase + lane;
        const int bn = s >> 3;
        const int bk = (s & 7) ^ (bn & 7);  // XOR-swizzled source (same 128B seg)
        const unsigned short* g =
            Wt + (size_t)(n0 + bn) * K + k0 + bk * 8;
        __builtin_amdgcn_global_load_lds(
            (const __attribute__((address_space(1))) void*)g,
            (__attribute__((address_space(3))) void*)(Bs + sbase * 8), 16, 0, 0);
      }
      __syncthreads();

#pragma unroll
      for (int kk = 0; kk < 2; ++kk) {
        bf16x8 a[4], b[4];
#pragma unroll
        for (int tm = 0; tm < 4; ++tm) {
          const int row = wr * 64 + tm * 16 + c;
          a[tm] = *(const bf16x8*)(As + (((kk * 4 + q) * 128) + row) * 8);
        }
#pragma unroll
        for (int tn = 0; tn < 4; ++tn) {
          const int n = wc * 64 + tn * 16 + c;
          b[tn] = *(const bf16x8*)(Bs + (n * 8 + ((kk * 4 + q) ^ (n & 7))) * 8);
        }
#pragma unroll
        for (int tm = 0; tm < 4; ++tm)
#pragma unroll
          for (int tn = 0; tn < 4; ++tn)
            acc[tm][tn] = __builtin_amdgcn_mfma_f32_16x16x32_bf16(
                a[tm], b[tn], acc[tm][tn], 0, 0, 0);
      }
      __syncthreads();
    }

    // C/D mapping: col=lane&15, row=quad*4+reg ; unscaled store
#pragma unroll
    for (int tm = 0; tm < 4; ++tm) {
#pragma unroll
      for (int r = 0; r < 4; ++r) {
        const int grow = m0 + wr * 64 + tm * 16 + q * 4 + r;
#pragma unroll
        for (int tn = 0; tn < 4; ++tn) {
          const int gcol = n0 + wc * 64 + tn * 16 + c;
          Hs[(size_t)grow * N + gcol] = f2bf(acc[tm][tn][r]);
        }
      }
    }
    return;
  }

  // ---- build_ell: one wave per node, popcount + lane prefix-scan.
  {
    const int wave = tid >> 6, lane = tid & 63;
    const int node = (bid - gemm_blocks) * 4 + wave;
    const unsigned* __restrict__ row = mask + (size_t)node * words;
    unsigned short* __restrict__ out = ell + (size_t)node * ELL_STRIDE;

    int running = 0;
    for (int r = 0; r < words; r += 64) {
      const int w = r + lane;
      unsigned bits = row[w];
      const int cnt = __popc(bits);
      int x = cnt;
#pragma unroll
      for (int d = 1; d < 64; d <<= 1) {
        int y = __shfl_up(x, d, 64);
        if (lane >= d) x += y;
      }
      int pos = running + x - cnt;
      while (bits) {
        const int b = __builtin_ctz(bits);
        bits &= bits - 1;
        if (pos < ELL_STRIDE) out[pos] = (unsigned short)((w << 5) + b);
        ++pos;
      }
      running += __shfl(x, 63, 64);
    }
    // self entry at [running], pads (index M -> dinv 0, zero row) after
    for (int p = running + lane; p < ELL_STRIDE; p += 64)
      out[p] = (unsigned short)(p == running ? node : M);
    if (lane == 0) {
      const int dd = running + 1;  // + self
      deg[node] = dd < ELL_STRIDE ? dd : ELL_STRIDE;
      dinv[node] = rsqrtf((float)running + 1.0f);
    }
  }
}

// ---- spmm: grid n/4 blocks, wave = one node, FULL D per entry.
// 64 lanes x 16B = 1KB = one full Hs row per iteration, fully coalesced.
// (byte_offset = j*2D, dinv[j]) staged once per wave as packed uint2 in LDS
// -> one broadcast ds_read_b64 + one add per iter on the gather path.
// Each lane owns 8 output columns -> no cross-lane reduce. unroll 16 keeps
// ~16 gathers in flight per wave (r5 lesson: latency-bound, not locality-
// bound -> raise MLP, don't chase cache residency).
__global__ __launch_bounds__(256) void spmm_kernel(
    const unsigned short* __restrict__ ell, const int* __restrict__ deg,
    const float* __restrict__ dinv, const unsigned short* __restrict__ Hs,
    const float* __restrict__ bias, float* __restrict__ out, int n, int D) {
  __shared__ uint2 ji[4][ELL_STRIDE];
  const int wave = threadIdx.x >> 6, lane = threadIdx.x & 63;
  const int i = blockIdx.x * 4 + wave;  // n divisible by 4
  const unsigned rowbytes = (unsigned)(D * 2);

  {  // stage (byte offset, dinv[j]) — 2 entries per lane; dinv is 32KB -> L1
    const unsigned j0 =
        __builtin_nontemporal_load(ell + (size_t)i * ELL_STRIDE + lane);
    const unsigned j1 =
        __builtin_nontemporal_load(ell + (size_t)i * ELL_STRIDE + 64 + lane);
    ji[wave][lane] = make_uint2(j0 * rowbytes, __float_as_uint(dinv[j0]));
    ji[wave][64 + lane] = make_uint2(j1 * rowbytes, __float_as_uint(dinv[j1]));
  }
  const int d = deg[i];             // includes the self entry
  const float di = dinv[i];
  const int kmax = (d + 15) & ~15;  // pads (dinv 0, zero row) cover the tail

  const char* __restrict__ hb = (const char*)(Hs + lane * 8);  // 16B/lane
  float acc[8] = {0.f, 0.f, 0.f, 0.f, 0.f, 0.f, 0.f, 0.f};

#pragma unroll 16
  for (int k = 0; k < kmax; ++k) {
    const uint2 e = ji[wave][k];  // uniform addr -> LDS broadcast
    const float dj = __uint_as_float(e.y);
    const uint4 hv = *(const uint4*)(hb + e.x);
    acc[0] += dj * bflo(hv.x); acc[1] += dj * bfhi(hv.x);
    acc[2] += dj * bflo(hv.y); acc[3] += dj * bfhi(hv.y);
    acc[4] += dj * bflo(hv.z); acc[5] += dj * bfhi(hv.z);
    acc[6] += dj * bflo(hv.w); acc[7] += dj * bfhi(hv.w);
  }

  const float4 b0 = *(const float4*)(bias + lane * 8);
  const float4 b1 = *(const float4*)(bias + lane * 8 + 4);
  float* op = out + (size_t)i * D + lane * 8;
  f32x4 o0, o1;
  o0.x = di * acc[0] + b0.x; o0.y = di * acc[1] + b0.y;
  o0.z = di * acc[2] + b0.z; o0.w = di * acc[3] + b0.w;
  o1.x = di * acc[4] + b1.x; o1.y = di * acc[5] + b1.y;
  o1.z = di * acc[6] + b1.z; o1.w = di * acc[7] + b1.w;
  __builtin_nontemporal_store(o0, (f32x4*)op);
  __builtin_nontemporal_store(o1, (f32x4*)(op + 4));
}

extern "C" void kernel_launch(void* const* d_in, const int* in_sizes, int n_in,
                              void* d_out, int out_size, void* d_ws, size_t ws_size,
                              hipStream_t stream) {
  const float* x    = (const float*)d_in[0];
  const int*   ei   = (const int*)d_in[1];
  const float* W    = (const float*)d_in[2];
  const float* bias = (const float*)d_in[3];
  float* out = (float*)d_out;

  const int d_out_dim = in_sizes[3];             // 512
  const int d_in_dim  = in_sizes[2] / d_out_dim; // 512
  const int n_nodes   = in_sizes[0] / d_in_dim;  // 8192
  const int n_edges   = in_sizes[1] / 2;         // 262144
  const int words     = (n_nodes + 31) / 32;     // 256

  // workspace layout (bytes)
  char* ws = (char*)d_ws;
  size_t off = 0;
  unsigned* mask = (unsigned*)(ws + off); off += (size_t)n_nodes * words * 4;       // 8 MB
  int* deg       = (int*)(ws + off);      off += (size_t)n_nodes * 4;               // 32 KB
  float* dinv    = (float*)(ws + off);    off += (size_t)(n_nodes + 1) * 4;         // 32 KB + pad
  unsigned short* ell = (unsigned short*)(ws + off); off += (size_t)n_nodes * ELL_STRIDE * 2; // 2 MB
  unsigned short* xb  = (unsigned short*)(ws + off); off += (size_t)n_nodes * d_in_dim * 2;   // 8 MB
  unsigned short* Wt  = (unsigned short*)(ws + off); off += (size_t)d_in_dim * d_out_dim * 2; // 512 KB
  unsigned short* Hs  = (unsigned short*)(ws + off);
  off += (size_t)(n_nodes + 1) * d_out_dim * 2;  // 8 MB + pad row

  hipMemsetAsync(mask, 0, (size_t)n_nodes * words * 4, stream);

  const int edge_blocks = (n_edges + 255) / 256;              // 1024
  const int n4 = n_nodes * d_in_dim / 4;
  const int cast_blocks = (n4 + 255) / 256;                   // 4096
  const int tr_blocks = (d_in_dim / 32) * (d_out_dim / 32);   // 256
  fused_front_kernel<<<edge_blocks + cast_blocks + tr_blocks + 1, 256, 0, stream>>>(
      ei, mask, n_edges, words, x, xb, n4, W, Wt, d_in_dim, d_out_dim,
      Hs, dinv, n_nodes, edge_blocks, cast_blocks, tr_blocks);

  const int nbx = d_out_dim / 128;                            // 4
  const int nbx_sh = 31 - __builtin_clz(nbx);                 // 2
  const int gemm_blocks = nbx * (n_nodes / 128);              // 256
  const int ell_blocks = n_nodes / 4;                         // 2048
  fused_mid_kernel<<<gemm_blocks + ell_blocks, 256, 0, stream>>>(
      xb, Wt, Hs, mask, ell, deg, dinv,
      n_nodes, d_out_dim, d_in_dim, words, gemm_blocks, nbx_sh);

  spmm_kernel<<<n_nodes / 4, 256, 0, stream>>>(ell, deg, dinv, Hs, bias, out,
                                               n_nodes, d_out_dim);
}